// Round 3
// baseline (299.964 us; speedup 1.0000x reference)
//
#include <hip/hip_runtime.h>

#define BB 8
#define NN 512
#define SS 96
#define HH 256
#define NHD 8
#define HDD 32
#define OUTD 4

// ws layout (floats)
#define Q_OFF   0
#define K_OFF   (4096*256)                 // 1048576
#define V_OFF   (K_OFF + 768*256)          // 1245184
#define CTX_OFF (V_OFF + 768*256)          // 1441792

// ============================================================
// GEMM stage: acc[4][QN] = A(16x256, LDS) @ W(NC x 256, global)^T
// Thread t: rows rg*4..rg*4+3 (rg = t>>6, wave-uniform -> A reads broadcast),
//           cols cj + 64*q (cj = t&63).
// W tiles staged to LDS with XOR float4-slot swizzle -> conflict-free b128.
// ============================================================
template<int QN>
__device__ __forceinline__ void gemm_stage(
    const float4* __restrict__ A4,      // LDS, [16][64] float4
    const float* __restrict__ Wg,       // global, [NC][256] f32
    float4* __restrict__ WT4,           // LDS, NC*8 float4
    int tid, float acc[4][QN])
{
    const int NC = QN * 64;
    const int rg = tid >> 6;
    const int cj = tid & 63;
    const int jsw = cj & 7;

    #pragma unroll
    for (int p = 0; p < 4; ++p)
        #pragma unroll
        for (int q = 0; q < QN; ++q) acc[p][q] = 0.f;

    for (int kt = 0; kt < 8; ++kt) {
        __syncthreads();
        // stage W[:, kt*32 .. kt*32+31]: row j, dest slot sd holds src slot sd^(j&7)
        {
            const int sd = tid & 7;
            for (int j = tid >> 3; j < NC; j += 32) {
                const int ss = sd ^ (j & 7);
                WT4[j * 8 + sd] = ((const float4*)(Wg + (size_t)j * HH))[kt * 8 + ss];
            }
        }
        __syncthreads();
        #pragma unroll
        for (int kk = 0; kk < 8; ++kk) {
            float4 a[4], w[QN];
            #pragma unroll
            for (int p = 0; p < 4; ++p)
                a[p] = A4[(rg * 4 + p) * 64 + kt * 8 + kk];   // broadcast (wave-uniform)
            #pragma unroll
            for (int q = 0; q < QN; ++q)
                w[q] = WT4[(cj + 64 * q) * 8 + (kk ^ jsw)];   // conflict-free
            #pragma unroll
            for (int p = 0; p < 4; ++p)
                #pragma unroll
                for (int q = 0; q < QN; ++q)
                    acc[p][q] += a[p].x * w[q].x + a[p].y * w[q].y
                               + a[p].z * w[q].z + a[p].w * w[q].w;
        }
    }
}

// ---------------- Kernel 1: fused projections ----------------
// blocks 0..255: spatial, 16 rows each -> q
// blocks 256..303: temporal, 16 rows each -> k, v
__global__ __launch_bounds__(256) void k_proj(
    const float* __restrict__ spatial, const float* __restrict__ temporal,
    const float* __restrict__ Ws, const float* __restrict__ bs,
    const float* __restrict__ Wt, const float* __restrict__ bt,
    const float* __restrict__ Win, const float* __restrict__ bin,
    float* __restrict__ q_out, float* __restrict__ k_out, float* __restrict__ v_out)
{
    __shared__ __align__(16) float A0[16][HH];
    __shared__ __align__(16) float MID[16][HH];
    __shared__ __align__(16) float4 WT4[HH * 8];   // 32 KB
    const int tid = threadIdx.x;
    const int rg = tid >> 6;
    const int cj = tid & 63;
    float acc[4][4];

    if (blockIdx.x < 256) {
        const int r0 = blockIdx.x * 16;
        const float4* g4 = (const float4*)(spatial + (size_t)r0 * HH);
        for (int i = tid; i < 16 * 64; i += 256) ((float4*)A0)[i] = g4[i];
        // (gemm_stage's leading barrier covers the A0 load)
        gemm_stage<4>((const float4*)A0, Ws, WT4, tid, acc);
        #pragma unroll
        for (int p = 0; p < 4; ++p)
            #pragma unroll
            for (int q = 0; q < 4; ++q)
                MID[rg * 4 + p][cj + 64 * q] = acc[p][q] + bs[cj + 64 * q];
        gemm_stage<4>((const float4*)MID, Win, WT4, tid, acc);   // Wq
        #pragma unroll
        for (int p = 0; p < 4; ++p)
            #pragma unroll
            for (int q = 0; q < 4; ++q)
                q_out[(size_t)(r0 + rg * 4 + p) * HH + cj + 64 * q] = acc[p][q] + bin[cj + 64 * q];
    } else {
        const int r0 = (blockIdx.x - 256) * 16;
        const float4* g4 = (const float4*)(temporal + (size_t)r0 * HH);
        for (int i = tid; i < 16 * 64; i += 256) ((float4*)A0)[i] = g4[i];
        gemm_stage<4>((const float4*)A0, Wt, WT4, tid, acc);
        #pragma unroll
        for (int p = 0; p < 4; ++p)
            #pragma unroll
            for (int q = 0; q < 4; ++q)
                MID[rg * 4 + p][cj + 64 * q] = acc[p][q] + bt[cj + 64 * q];
        gemm_stage<4>((const float4*)MID, Win + (size_t)HH * HH, WT4, tid, acc);  // Wk
        #pragma unroll
        for (int p = 0; p < 4; ++p)
            #pragma unroll
            for (int q = 0; q < 4; ++q)
                k_out[(size_t)(r0 + rg * 4 + p) * HH + cj + 64 * q] = acc[p][q] + bin[HH + cj + 64 * q];
        gemm_stage<4>((const float4*)MID, Win + (size_t)2 * HH * HH, WT4, tid, acc);  // Wv
        #pragma unroll
        for (int p = 0; p < 4; ++p)
            #pragma unroll
            for (int q = 0; q < 4; ++q)
                v_out[(size_t)(r0 + rg * 4 + p) * HH + cj + 64 * q] = acc[p][q] + bin[2 * HH + cj + 64 * q];
    }
}

// ---------------- Kernel 2: attention ----------------
// grid 256 blocks x 256 threads; 128 rows/block, 2 threads/row (split S)
__global__ __launch_bounds__(256) void k_attn(
    const float* __restrict__ qg, const float* __restrict__ kg,
    const float* __restrict__ vg, float* __restrict__ ctxg)
{
    __shared__ __align__(16) float kl[SS][HDD];
    __shared__ __align__(16) float vl[SS][HDD];
    const int tid = threadIdx.x;
    const int blk = blockIdx.x;
    const int cc = blk & 3;
    const int h = (blk >> 2) & (NHD - 1);
    const int b = blk >> 5;

    for (int i = tid; i < SS * HDD / 4; i += 256) {
        int s = i >> 3, d4 = i & 7;
        ((float4*)kl[s])[d4] = *(const float4*)(kg + (size_t)(b * SS + s) * HH + h * HDD + d4 * 4);
        ((float4*)vl[s])[d4] = *(const float4*)(vg + (size_t)(b * SS + s) * HH + h * HDD + d4 * 4);
    }
    __syncthreads();

    const int hf = tid & 1;
    const int r = tid >> 1;
    const int n = cc * 128 + r;
    const float4* q4 = (const float4*)(qg + (size_t)(b * NN + n) * HH + h * HDD);
    float4 q[8];
    #pragma unroll
    for (int i = 0; i < 8; ++i) q[i] = q4[i];

    const float scale = 0.17677669529663687f;  // 1/sqrt(32)
    float sum = 0.f;
    float4 ctx[8] = {};
    const int s0 = hf * 48;
    for (int s = s0; s < s0 + 48; ++s) {
        float dot = 0.f;
        #pragma unroll
        for (int i = 0; i < 8; ++i) {
            float4 kk = ((const float4*)kl[s])[i];
            dot += q[i].x * kk.x + q[i].y * kk.y + q[i].z * kk.z + q[i].w * kk.w;
        }
        float p = __expf(dot * scale);   // logits are O(0.1): no max-subtract needed
        sum += p;
        #pragma unroll
        for (int i = 0; i < 8; ++i) {
            float4 vv = ((const float4*)vl[s])[i];
            ctx[i].x += p * vv.x; ctx[i].y += p * vv.y;
            ctx[i].z += p * vv.z; ctx[i].w += p * vv.w;
        }
    }
    sum += __shfl_xor(sum, 1);
    #pragma unroll
    for (int i = 0; i < 8; ++i) {
        ctx[i].x += __shfl_xor(ctx[i].x, 1);
        ctx[i].y += __shfl_xor(ctx[i].y, 1);
        ctx[i].z += __shfl_xor(ctx[i].z, 1);
        ctx[i].w += __shfl_xor(ctx[i].w, 1);
    }
    float inv = 1.0f / sum;
    float4* o4 = (float4*)(ctxg + (size_t)(b * NN + n) * HH + h * HDD);
    #pragma unroll
    for (int i = 0; i < 4; ++i) {
        int idx = hf * 4 + i;
        o4[idx] = make_float4(ctx[idx].x * inv, ctx[idx].y * inv,
                              ctx[idx].z * inv, ctx[idx].w * inv);
    }
}

// ---------------- Kernel 3: head MLP + broadcast ----------------
// grid 256 blocks x 256 threads, 16 rows/block
__global__ __launch_bounds__(256) void k_head(
    const float* __restrict__ ctxg,
    const float* __restrict__ Wao, const float* __restrict__ bao,
    const float* __restrict__ W1, const float* __restrict__ b1,
    const float* __restrict__ Wo1, const float* __restrict__ bo1,
    const float* __restrict__ Wo2, const float* __restrict__ bo2,
    float* __restrict__ out)
{
    __shared__ __align__(16) float A0[16][HH];
    __shared__ __align__(16) float MID[16][HH];
    __shared__ __align__(16) float4 WT4[HH * 8];   // 32 KB
    __shared__ __align__(16) float y[16][OUTD];
    const int tid = threadIdx.x;
    const int rg = tid >> 6;
    const int cj = tid & 63;
    const int r0 = blockIdx.x * 16;
    float acc[4][4];

    const float4* g4 = (const float4*)(ctxg + (size_t)r0 * HH);
    for (int i = tid; i < 16 * 64; i += 256) ((float4*)A0)[i] = g4[i];

    // stage 1: attended = ctx @ Wao.T + bao -> MID
    gemm_stage<4>((const float4*)A0, Wao, WT4, tid, acc);
    #pragma unroll
    for (int p = 0; p < 4; ++p)
        #pragma unroll
        for (int q = 0; q < 4; ++q)
            MID[rg * 4 + p][cj + 64 * q] = acc[p][q] + bao[cj + 64 * q];

    // stage 2: fused = relu(attended @ W1.T + b1) -> A0 (ctx dead now)
    gemm_stage<4>((const float4*)MID, W1, WT4, tid, acc);
    __syncthreads();   // everyone done reading MID's consumer? (A0 overwrite is safe: stage1 done)
    #pragma unroll
    for (int p = 0; p < 4; ++p)
        #pragma unroll
        for (int q = 0; q < 4; ++q)
            A0[rg * 4 + p][cj + 64 * q] = fmaxf(acc[p][q] + b1[cj + 64 * q], 0.f);

    // stage 3: h2 = relu(fused @ Wo1.T + bo1) -> MID[.][0..127]
    gemm_stage<2>((const float4*)A0, Wo1, WT4, tid, (float(*)[2])acc);
    __syncthreads();
    {
        float (*acc2)[2] = (float(*)[2])acc;
        #pragma unroll
        for (int p = 0; p < 4; ++p)
            #pragma unroll
            for (int q = 0; q < 2; ++q)
                MID[rg * 4 + p][cj + 64 * q] = fmaxf(acc2[p][q] + bo1[cj + 64 * q], 0.f);
    }
    __syncthreads();

    // stage 4: y = h2 @ Wo2.T + bo2 (16 rows x 4 outs, dots of 128)
    if (tid < 64) {
        int r = tid >> 2, o = tid & 3;
        float a = 0.f;
        const float4* w4 = (const float4*)(Wo2 + (size_t)o * (HH / 2));
        const float4* h4 = (const float4*)MID[r];
        for (int kk = 0; kk < 32; ++kk) {
            float4 w = w4[kk], hv = h4[kk];
            a += hv.x * w.x + hv.y * w.y + hv.z * w.z + hv.w * w.w;
        }
        y[r][o] = a + bo2[o];
    }
    __syncthreads();

    // broadcast: out[b][s][nbase+r][:] = y[r]
    const int b = r0 >> 9;
    const int nbase = r0 & 511;
    for (int i = tid; i < 16 * SS; i += 256) {
        int s = i >> 4;
        int r = i & 15;
        *(float4*)(out + ((size_t)(b * SS + s) * NN + (nbase + r)) * OUTD) = *(const float4*)y[r];
    }
}

extern "C" void kernel_launch(void* const* d_in, const int* in_sizes, int n_in,
                              void* d_out, int out_size, void* d_ws, size_t ws_size,
                              hipStream_t stream) {
    const float* spatial  = (const float*)d_in[0];
    const float* temporal = (const float*)d_in[1];
    const float* Ws  = (const float*)d_in[2];
    const float* bs  = (const float*)d_in[3];
    const float* Wt  = (const float*)d_in[4];
    const float* bt  = (const float*)d_in[5];
    const float* Win = (const float*)d_in[6];
    const float* bin = (const float*)d_in[7];
    const float* Wao = (const float*)d_in[8];
    const float* bao = (const float*)d_in[9];
    const float* W1  = (const float*)d_in[10];
    const float* b1  = (const float*)d_in[11];
    const float* Wo1 = (const float*)d_in[12];
    const float* bo1 = (const float*)d_in[13];
    const float* Wo2 = (const float*)d_in[14];
    const float* bo2 = (const float*)d_in[15];
    float* out = (float*)d_out;
    float* ws  = (float*)d_ws;

    float* qbuf   = ws + Q_OFF;
    float* kbuf   = ws + K_OFF;
    float* vbuf   = ws + V_OFF;
    float* ctxbuf = ws + CTX_OFF;

    hipLaunchKernelGGL(k_proj, dim3(304), dim3(256), 0, stream,
                       spatial, temporal, Ws, bs, Wt, bt, Win, bin,
                       qbuf, kbuf, vbuf);
    hipLaunchKernelGGL(k_attn, dim3(BB * NHD * 4), dim3(256), 0, stream,
                       qbuf, kbuf, vbuf, ctxbuf);
    hipLaunchKernelGGL(k_head, dim3(BB * NN / 16), dim3(256), 0, stream,
                       ctxbuf, Wao, bao, W1, b1, Wo1, bo1, Wo2, bo2, out);
}

// Round 4
// 152.089 us; speedup vs baseline: 1.9723x; 1.9723x over previous
//
#include <hip/hip_runtime.h>

#define BB 8
#define NN 512
#define SS 96
#define HH 256
#define NHD 8
#define HDD 32
#define OUTD 4

// ws layout: fp32 region (float offsets)
#define Q_OFF   0
#define K_OFF   (4096*256)                 // 1048576
#define V_OFF   (K_OFF + 768*256)          // 1245184
#define CTX_OFF (V_OFF + 768*256)          // 1441792
#define BF_BASE (CTX_OFF + 4096*256)       // 2490368 floats -> byte 9961472 (16B aligned)
// bf16 region (ushort offsets within BF region)
#define WSB_OFF  0
#define WTB_OFF  65536
#define WINB_OFF 131072
#define WAOB_OFF 327680
#define W1B_OFF  393216
#define WO1B_OFF 458752
#define BF_TOTAL 491520

typedef __attribute__((ext_vector_type(8))) short bf16x8;
typedef __attribute__((ext_vector_type(4))) float f32x4;

__device__ __forceinline__ unsigned short f2bf(float f) {
    unsigned int u = __float_as_uint(f);
    u = (u + 0x7FFFu + ((u >> 16) & 1u)) >> 16;   // RNE
    return (unsigned short)u;
}

// ---------------- k_cast: fp32 weights -> bf16 in ws ----------------
__global__ __launch_bounds__(256) void k_cast(
    const float* __restrict__ Ws, const float* __restrict__ Wt,
    const float* __restrict__ Win, const float* __restrict__ Wao,
    const float* __restrict__ W1, const float* __restrict__ Wo1,
    unsigned short* __restrict__ dst)
{
    int idx = blockIdx.x * 256 + threadIdx.x;
    for (int j4 = idx; j4 < BF_TOTAL / 4; j4 += 120 * 256) {
        int e = j4 * 4;
        const float* src; int off;
        if (e < 65536)       { src = Ws;  off = e; }
        else if (e < 131072) { src = Wt;  off = e - 65536; }
        else if (e < 327680) { src = Win; off = e - 131072; }
        else if (e < 393216) { src = Wao; off = e - 327680; }
        else if (e < 458752) { src = W1;  off = e - 393216; }
        else                 { src = Wo1; off = e - 458752; }
        float4 v = *(const float4*)(src + off);
        ushort4 o;
        o.x = f2bf(v.x); o.y = f2bf(v.y); o.z = f2bf(v.z); o.w = f2bf(v.w);
        *(ushort4*)(dst + e) = o;
    }
}

// ============================================================
// MFMA stage helpers. Block = 256 thr / 4 waves, 16-row tile, NC out cols.
// A in LDS as bf16 [16][256], 16B-slot XOR swizzle: slot' = slot ^ (row&7).
// W: bf16 global [NC][256] row-major (= B^T input, m92 pattern).
// Wave w owns cols [w*NCT*16, (w+1)*NCT*16).
// ============================================================
template<int NCT>
__device__ __forceinline__ void mfma_stage(
    const unsigned short* __restrict__ Asw,
    const unsigned short* __restrict__ Wb,
    int lane, int wave, f32x4 acc[NCT])
{
    const int row = lane & 15, kq = lane >> 4;
    #pragma unroll
    for (int ct = 0; ct < NCT; ++ct) acc[ct] = (f32x4){0.f, 0.f, 0.f, 0.f};
    #pragma unroll 2
    for (int kt = 0; kt < 8; ++kt) {
        const int slot = kt * 4 + kq;
        bf16x8 a = *(const bf16x8*)(Asw + row * 256 + ((slot ^ (row & 7)) << 3));
        #pragma unroll
        for (int ct = 0; ct < NCT; ++ct) {
            const unsigned short* wp =
                Wb + (size_t)((wave * NCT + ct) * 16 + row) * 256 + kt * 32 + kq * 8;
            bf16x8 b = *(const bf16x8*)wp;
            acc[ct] = __builtin_amdgcn_mfma_f32_16x16x32_bf16(a, b, acc[ct], 0, 0, 0);
        }
    }
}

// epilogue -> LDS bf16 (swizzled), optional relu
template<int NCT, bool RELU>
__device__ __forceinline__ void epi_lds(
    unsigned short* __restrict__ OutSw, const float* __restrict__ bias,
    int lane, int wave, const f32x4 acc[NCT])
{
    const int col0 = lane & 15, rq = lane >> 4;
    #pragma unroll
    for (int ct = 0; ct < NCT; ++ct) {
        const int C = wave * NCT * 16 + ct * 16 + col0;
        const float bb = bias[C];
        const int slot = C >> 3, within = C & 7;
        #pragma unroll
        for (int r = 0; r < 4; ++r) {
            const int R = rq * 4 + r;
            float v = acc[ct][r] + bb;
            if (RELU) v = fmaxf(v, 0.f);
            OutSw[R * 256 + ((slot ^ (R & 7)) << 3) + within] = f2bf(v);
        }
    }
}

// epilogue -> global fp32 [16][256]
template<int NCT>
__device__ __forceinline__ void epi_global(
    float* __restrict__ Og, const float* __restrict__ bias,
    int lane, int wave, const f32x4 acc[NCT])
{
    const int col0 = lane & 15, rq = lane >> 4;
    #pragma unroll
    for (int ct = 0; ct < NCT; ++ct) {
        const int C = wave * NCT * 16 + ct * 16 + col0;
        const float bb = bias[C];
        #pragma unroll
        for (int r = 0; r < 4; ++r) {
            const int R = rq * 4 + r;
            Og[(size_t)R * 256 + C] = acc[ct][r] + bb;
        }
    }
}

// stage fp32 global [16][256] -> LDS bf16 swizzled
__device__ __forceinline__ void stage_A(
    const float* __restrict__ Ag, unsigned short* __restrict__ Asw, int tid)
{
    #pragma unroll
    for (int ii = 0; ii < 4; ++ii) {
        int i = tid + ii * 256;
        int row = i >> 6, c4 = i & 63;
        float4 v = ((const float4*)(Ag + (size_t)row * 256))[c4];
        int col = c4 * 4;
        int slot = col >> 3, half = (col >> 2) & 1;
        ushort4 o;
        o.x = f2bf(v.x); o.y = f2bf(v.y); o.z = f2bf(v.z); o.w = f2bf(v.w);
        *(ushort4*)(Asw + row * 256 + ((slot ^ (row & 7)) << 3) + half * 4) = o;
    }
}

// ---------------- Kernel 1: fused projections (MFMA) ----------------
// blocks 0..255: spatial 16 rows -> q ; blocks 256..303: temporal 16 rows -> k,v
__global__ __launch_bounds__(256) void k_proj(
    const float* __restrict__ spatial, const float* __restrict__ temporal,
    const float* __restrict__ bs, const float* __restrict__ bt,
    const float* __restrict__ bin,
    const unsigned short* __restrict__ bfw,
    float* __restrict__ q_out, float* __restrict__ k_out, float* __restrict__ v_out)
{
    __shared__ __align__(16) unsigned short A0[16 * 256];
    __shared__ __align__(16) unsigned short MID[16 * 256];
    const int tid = threadIdx.x, lane = tid & 63, wave = tid >> 6;
    f32x4 acc[4];

    if (blockIdx.x < 256) {
        const int r0 = blockIdx.x * 16;
        stage_A(spatial + (size_t)r0 * 256, A0, tid);
        __syncthreads();
        mfma_stage<4>(A0, bfw + WSB_OFF, lane, wave, acc);
        epi_lds<4, false>(MID, bs, lane, wave, acc);
        __syncthreads();
        mfma_stage<4>(MID, bfw + WINB_OFF, lane, wave, acc);          // Wq
        epi_global<4>(q_out + (size_t)r0 * 256, bin, lane, wave, acc);
    } else {
        const int r0 = (blockIdx.x - 256) * 16;
        stage_A(temporal + (size_t)r0 * 256, A0, tid);
        __syncthreads();
        mfma_stage<4>(A0, bfw + WTB_OFF, lane, wave, acc);
        epi_lds<4, false>(MID, bt, lane, wave, acc);
        __syncthreads();
        mfma_stage<4>(MID, bfw + WINB_OFF + 65536, lane, wave, acc);  // Wk
        epi_global<4>(k_out + (size_t)r0 * 256, bin + 256, lane, wave, acc);
        mfma_stage<4>(MID, bfw + WINB_OFF + 131072, lane, wave, acc); // Wv
        epi_global<4>(v_out + (size_t)r0 * 256, bin + 512, lane, wave, acc);
    }
}

// ---------------- Kernel 2: attention (fp32, unchanged from R2) ----------------
__global__ __launch_bounds__(256) void k_attn(
    const float* __restrict__ qg, const float* __restrict__ kg,
    const float* __restrict__ vg, float* __restrict__ ctxg)
{
    __shared__ __align__(16) float kl[SS][HDD];
    __shared__ __align__(16) float vl[SS][HDD];
    const int tid = threadIdx.x;
    const int blk = blockIdx.x;
    const int cc = blk & 3;
    const int h = (blk >> 2) & (NHD - 1);
    const int b = blk >> 5;

    for (int i = tid; i < SS * HDD / 4; i += 256) {
        int s = i >> 3, d4 = i & 7;
        ((float4*)kl[s])[d4] = *(const float4*)(kg + (size_t)(b * SS + s) * HH + h * HDD + d4 * 4);
        ((float4*)vl[s])[d4] = *(const float4*)(vg + (size_t)(b * SS + s) * HH + h * HDD + d4 * 4);
    }
    __syncthreads();

    const int hf = tid & 1;
    const int r = tid >> 1;
    const int n = cc * 128 + r;
    const float4* q4 = (const float4*)(qg + (size_t)(b * NN + n) * HH + h * HDD);
    float4 q[8];
    #pragma unroll
    for (int i = 0; i < 8; ++i) q[i] = q4[i];

    const float scale = 0.17677669529663687f;  // 1/sqrt(32)
    float sum = 0.f;
    float4 ctx[8] = {};
    const int s0 = hf * 48;
    for (int s = s0; s < s0 + 48; ++s) {
        float dot = 0.f;
        #pragma unroll
        for (int i = 0; i < 8; ++i) {
            float4 kk = ((const float4*)kl[s])[i];
            dot += q[i].x * kk.x + q[i].y * kk.y + q[i].z * kk.z + q[i].w * kk.w;
        }
        float p = __expf(dot * scale);   // logits O(0.1): no max-subtract needed
        sum += p;
        #pragma unroll
        for (int i = 0; i < 8; ++i) {
            float4 vv = ((const float4*)vl[s])[i];
            ctx[i].x += p * vv.x; ctx[i].y += p * vv.y;
            ctx[i].z += p * vv.z; ctx[i].w += p * vv.w;
        }
    }
    sum += __shfl_xor(sum, 1);
    #pragma unroll
    for (int i = 0; i < 8; ++i) {
        ctx[i].x += __shfl_xor(ctx[i].x, 1);
        ctx[i].y += __shfl_xor(ctx[i].y, 1);
        ctx[i].z += __shfl_xor(ctx[i].z, 1);
        ctx[i].w += __shfl_xor(ctx[i].w, 1);
    }
    float inv = 1.0f / sum;
    float4* o4 = (float4*)(ctxg + (size_t)(b * NN + n) * HH + h * HDD);
    #pragma unroll
    for (int i = 0; i < 4; ++i) {
        int idx = hf * 4 + i;
        o4[idx] = make_float4(ctx[idx].x * inv, ctx[idx].y * inv,
                              ctx[idx].z * inv, ctx[idx].w * inv);
    }
}

// ---------------- Kernel 3: head MLP (MFMA) + broadcast ----------------
__global__ __launch_bounds__(256) void k_head(
    const float* __restrict__ ctxg,
    const float* __restrict__ bao, const float* __restrict__ b1,
    const float* __restrict__ bo1,
    const float* __restrict__ Wo2, const float* __restrict__ bo2,
    const unsigned short* __restrict__ bfw,
    float* __restrict__ out)
{
    __shared__ __align__(16) unsigned short A0[16 * 256];
    __shared__ __align__(16) unsigned short MID[16 * 256];
    __shared__ __align__(16) float H2[16 * 128];
    __shared__ __align__(16) float y[16][OUTD];
    const int tid = threadIdx.x, lane = tid & 63, wave = tid >> 6;
    const int r0 = blockIdx.x * 16;
    f32x4 acc[4];

    stage_A(ctxg + (size_t)r0 * 256, A0, tid);
    __syncthreads();
    // stage 1: attended = ctx @ Wao.T + bao -> MID (bf16)
    mfma_stage<4>(A0, bfw + WAOB_OFF, lane, wave, acc);
    epi_lds<4, false>(MID, bao, lane, wave, acc);
    __syncthreads();
    // stage 2: fused = relu(attended @ W1.T + b1) -> A0 (bf16; A0 dead after barrier)
    mfma_stage<4>(MID, bfw + W1B_OFF, lane, wave, acc);
    epi_lds<4, true>(A0, b1, lane, wave, acc);
    __syncthreads();
    // stage 3: h2 = relu(fused @ Wo1.T + bo1) -> H2 (fp32, NC=128)
    {
        f32x4 a2[2];
        mfma_stage<2>(A0, bfw + WO1B_OFF, lane, wave, a2);
        const int col0 = lane & 15, rq = lane >> 4;
        #pragma unroll
        for (int ct = 0; ct < 2; ++ct) {
            const int C = wave * 32 + ct * 16 + col0;
            const float bb = bo1[C];
            #pragma unroll
            for (int r = 0; r < 4; ++r) {
                const int R = rq * 4 + r;
                H2[R * 128 + C] = fmaxf(a2[ct][r] + bb, 0.f);
            }
        }
    }
    __syncthreads();
    // stage 4: y = h2 @ Wo2.T + bo2 (fp32, dots of 128)
    if (tid < 64) {
        int r = tid >> 2, o = tid & 3;
        float a = 0.f;
        const float4* w4 = (const float4*)(Wo2 + (size_t)o * 128);
        const float4* h4 = (const float4*)(H2 + r * 128);
        for (int kk = 0; kk < 32; ++kk) {
            float4 w = w4[kk], hv = h4[kk];
            a += hv.x * w.x + hv.y * w.y + hv.z * w.z + hv.w * w.w;
        }
        y[r][o] = a + bo2[o];
    }
    __syncthreads();
    // broadcast: out[b][s][nbase+r][:] = y[r]
    const int b = r0 >> 9;
    const int nbase = r0 & 511;
    for (int i = tid; i < 16 * SS; i += 256) {
        int s = i >> 4;
        int r = i & 15;
        *(float4*)(out + ((size_t)(b * SS + s) * NN + (nbase + r)) * OUTD) = *(const float4*)y[r];
    }
}

extern "C" void kernel_launch(void* const* d_in, const int* in_sizes, int n_in,
                              void* d_out, int out_size, void* d_ws, size_t ws_size,
                              hipStream_t stream) {
    const float* spatial  = (const float*)d_in[0];
    const float* temporal = (const float*)d_in[1];
    const float* Ws  = (const float*)d_in[2];
    const float* bs  = (const float*)d_in[3];
    const float* Wt  = (const float*)d_in[4];
    const float* bt  = (const float*)d_in[5];
    const float* Win = (const float*)d_in[6];
    const float* bin = (const float*)d_in[7];
    const float* Wao = (const float*)d_in[8];
    const float* bao = (const float*)d_in[9];
    const float* W1  = (const float*)d_in[10];
    const float* b1  = (const float*)d_in[11];
    const float* Wo1 = (const float*)d_in[12];
    const float* bo1 = (const float*)d_in[13];
    const float* Wo2 = (const float*)d_in[14];
    const float* bo2 = (const float*)d_in[15];
    float* out = (float*)d_out;
    float* ws  = (float*)d_ws;

    float* qbuf   = ws + Q_OFF;
    float* kbuf   = ws + K_OFF;
    float* vbuf   = ws + V_OFF;
    float* ctxbuf = ws + CTX_OFF;
    unsigned short* bfw = (unsigned short*)(ws + BF_BASE);

    hipLaunchKernelGGL(k_cast, dim3(120), dim3(256), 0, stream,
                       Ws, Wt, Win, Wao, W1, Wo1, bfw);
    hipLaunchKernelGGL(k_proj, dim3(304), dim3(256), 0, stream,
                       spatial, temporal, bs, bt, bin, bfw, qbuf, kbuf, vbuf);
    hipLaunchKernelGGL(k_attn, dim3(BB * NHD * 4), dim3(256), 0, stream,
                       qbuf, kbuf, vbuf, ctxbuf);
    hipLaunchKernelGGL(k_head, dim3(BB * NN / 16), dim3(256), 0, stream,
                       ctxbuf, bao, b1, bo1, Wo2, bo2, bfw, out);
}

// Round 6
// 127.125 us; speedup vs baseline: 2.3596x; 1.1964x over previous
//
#include <hip/hip_runtime.h>

#define BB 8
#define NN 512
#define SS 96
#define HH 256
#define NHD 8
#define HDD 32
#define OUTD 4

// ws layout, ushort offsets from ws base
#define WSB_OFF  0
#define WTB_OFF  65536
#define WINB_OFF 131072
#define WAOB_OFF 327680
#define W1B_OFF  393216
#define WO1B_OFF 458752
#define BF_TOTAL 491520
#define QB_OFF   491520                    // 4096*256 bf16 q
#define KB_OFF   (QB_OFF + 1048576)        // 768*256 bf16 k
#define VTB_OFF  (KB_OFF + 196608)         // [B][256][96] bf16 v-transposed

typedef __attribute__((ext_vector_type(8))) short bf16x8;
typedef __attribute__((ext_vector_type(4))) float f32x4;

__device__ __forceinline__ unsigned short f2bf(float f) {
    unsigned int u = __float_as_uint(f);
    u = (u + 0x7FFFu + ((u >> 16) & 1u)) >> 16;   // RNE
    return (unsigned short)u;
}

// ---------------- k_cast: fp32 weights -> bf16 in ws ----------------
__global__ __launch_bounds__(256) void k_cast(
    const float* __restrict__ Ws, const float* __restrict__ Wt,
    const float* __restrict__ Win, const float* __restrict__ Wao,
    const float* __restrict__ W1, const float* __restrict__ Wo1,
    unsigned short* __restrict__ dst)
{
    int idx = blockIdx.x * 256 + threadIdx.x;
    for (int j4 = idx; j4 < BF_TOTAL / 4; j4 += 120 * 256) {
        int e = j4 * 4;
        const float* src; int off;
        if (e < 65536)       { src = Ws;  off = e; }
        else if (e < 131072) { src = Wt;  off = e - 65536; }
        else if (e < 327680) { src = Win; off = e - 131072; }
        else if (e < 393216) { src = Wao; off = e - 327680; }
        else if (e < 458752) { src = W1;  off = e - 393216; }
        else                 { src = Wo1; off = e - 458752; }
        float4 v = *(const float4*)(src + off);
        ushort4 o;
        o.x = f2bf(v.x); o.y = f2bf(v.y); o.z = f2bf(v.z); o.w = f2bf(v.w);
        *(ushort4*)(dst + e) = o;
    }
}

// ============================================================
// MFMA helpers (validated R4). Block = 256 thr / 4 waves, 16-row A tile.
// A in LDS bf16 [16][256], 16B-slot XOR swizzle: slot' = slot ^ (row&7).
// W: bf16 global [NC][256] row-major (B^T input, m92 pattern).
// ============================================================
template<int NCT>
__device__ __forceinline__ void mfma_stage(
    const unsigned short* __restrict__ Asw,
    const unsigned short* __restrict__ Wb,
    int lane, int wave, f32x4 acc[NCT])
{
    const int row = lane & 15, kq = lane >> 4;
    #pragma unroll
    for (int ct = 0; ct < NCT; ++ct) acc[ct] = (f32x4){0.f, 0.f, 0.f, 0.f};
    #pragma unroll 2
    for (int kt = 0; kt < 8; ++kt) {
        const int slot = kt * 4 + kq;
        bf16x8 a = *(const bf16x8*)(Asw + row * 256 + ((slot ^ (row & 7)) << 3));
        #pragma unroll
        for (int ct = 0; ct < NCT; ++ct) {
            const unsigned short* wp =
                Wb + (size_t)((wave * NCT + ct) * 16 + row) * 256 + kt * 32 + kq * 8;
            bf16x8 b = *(const bf16x8*)wp;
            acc[ct] = __builtin_amdgcn_mfma_f32_16x16x32_bf16(a, b, acc[ct], 0, 0, 0);
        }
    }
}

template<int NCT, bool RELU>
__device__ __forceinline__ void epi_lds(
    unsigned short* __restrict__ OutSw, const float* __restrict__ bias,
    int lane, int wave, const f32x4 acc[NCT])
{
    const int col0 = lane & 15, rq = lane >> 4;
    #pragma unroll
    for (int ct = 0; ct < NCT; ++ct) {
        const int C = wave * NCT * 16 + ct * 16 + col0;
        const float bb = bias[C];
        const int slot = C >> 3, within = C & 7;
        #pragma unroll
        for (int r = 0; r < 4; ++r) {
            const int R = rq * 4 + r;
            float v = acc[ct][r] + bb;
            if (RELU) v = fmaxf(v, 0.f);
            OutSw[R * 256 + ((slot ^ (R & 7)) << 3) + within] = f2bf(v);
        }
    }
}

// epilogue -> global bf16 [16][256]
template<int NCT>
__device__ __forceinline__ void epi_gbf16(
    unsigned short* __restrict__ Og, const float* __restrict__ bias,
    int lane, int wave, const f32x4 acc[NCT])
{
    const int col0 = lane & 15, rq = lane >> 4;
    #pragma unroll
    for (int ct = 0; ct < NCT; ++ct) {
        const int C = wave * NCT * 16 + ct * 16 + col0;
        const float bb = bias[C];
        #pragma unroll
        for (int r = 0; r < 4; ++r) {
            const int R = rq * 4 + r;
            Og[(size_t)R * 256 + C] = f2bf(acc[ct][r] + bb);
        }
    }
}

// stage fp32 global [16][256] -> LDS bf16 swizzled
__device__ __forceinline__ void stage_A(
    const float* __restrict__ Ag, unsigned short* __restrict__ Asw, int tid)
{
    #pragma unroll
    for (int ii = 0; ii < 4; ++ii) {
        int i = tid + ii * 256;
        int row = i >> 6, c4 = i & 63;
        float4 v = ((const float4*)(Ag + (size_t)row * 256))[c4];
        int col = c4 * 4;
        int slot = col >> 3, half = (col >> 2) & 1;
        ushort4 o;
        o.x = f2bf(v.x); o.y = f2bf(v.y); o.z = f2bf(v.z); o.w = f2bf(v.w);
        *(ushort4*)(Asw + row * 256 + ((slot ^ (row & 7)) << 3) + half * 4) = o;
    }
}

// ---------------- Kernel 1: projections -> bf16 q, k, vT ----------------
// blocks 0..255: spatial 16 rows -> q ; blocks 256..303: temporal 16 rows -> k, vT
__global__ __launch_bounds__(256) void k_qkv(
    const float* __restrict__ spatial, const float* __restrict__ temporal,
    const float* __restrict__ bs, const float* __restrict__ bt,
    const float* __restrict__ bin,
    const unsigned short* __restrict__ bfw,
    unsigned short* __restrict__ qb, unsigned short* __restrict__ kb,
    unsigned short* __restrict__ vtb)
{
    __shared__ __align__(16) unsigned short A0[16 * 256];
    __shared__ __align__(16) unsigned short MID[16 * 256];
    const int tid = threadIdx.x, lane = tid & 63, wave = tid >> 6;
    f32x4 acc[4];

    if (blockIdx.x < 256) {
        const int r0 = blockIdx.x * 16;
        stage_A(spatial + (size_t)r0 * 256, A0, tid);
        __syncthreads();
        mfma_stage<4>(A0, bfw + WSB_OFF, lane, wave, acc);
        epi_lds<4, false>(MID, bs, lane, wave, acc);
        __syncthreads();
        mfma_stage<4>(MID, bfw + WINB_OFF, lane, wave, acc);          // Wq
        epi_gbf16<4>(qb + (size_t)r0 * 256, bin, lane, wave, acc);
    } else {
        const int r0 = (blockIdx.x - 256) * 16;   // temporal row (16 | 96, so one batch)
        stage_A(temporal + (size_t)r0 * 256, A0, tid);
        __syncthreads();
        mfma_stage<4>(A0, bfw + WTB_OFF, lane, wave, acc);
        epi_lds<4, false>(MID, bt, lane, wave, acc);
        __syncthreads();
        mfma_stage<4>(MID, bfw + WINB_OFF + 65536, lane, wave, acc);  // Wk
        epi_gbf16<4>(kb + (size_t)r0 * 256, bin + 256, lane, wave, acc);
        mfma_stage<4>(MID, bfw + WINB_OFF + 131072, lane, wave, acc); // Wv
        {   // vT epilogue: vtb[(b*256 + C)*96 + s]
            const int bb_ = r0 / 96, s0 = r0 % 96;
            const int col0 = lane & 15, rq = lane >> 4;
            #pragma unroll
            for (int ct = 0; ct < 4; ++ct) {
                const int C = wave * 64 + ct * 16 + col0;
                const float bv = bin[512 + C];
                #pragma unroll
                for (int r = 0; r < 4; ++r) {
                    const int R = rq * 4 + r;
                    vtb[((size_t)(bb_ * 256 + C)) * 96 + s0 + R] = f2bf(acc[ct][r] + bv);
                }
            }
        }
    }
}

// ---------------- Kernel 2: fused attention + head MLP + broadcast ----------------
// grid B * N/16 = 256 blocks x 256 thr (4 waves). Wave w handles heads {2w, 2w+1}.
__global__ __launch_bounds__(256) void k_attnhead(
    const unsigned short* __restrict__ qb, const unsigned short* __restrict__ kb,
    const unsigned short* __restrict__ vtb, const unsigned short* __restrict__ bfw,
    const float* __restrict__ bao, const float* __restrict__ b1,
    const float* __restrict__ bo1,
    const float* __restrict__ Wo2, const float* __restrict__ bo2,
    float* __restrict__ out)
{
    __shared__ __align__(16) unsigned short A0[16 * 256];      // ctx, bf16 swizzled
    __shared__ __align__(16) unsigned short MID[16 * 256];
    __shared__ __align__(16) float H2[16 * 128];
    __shared__ __align__(16) unsigned short P[4][16 * 104];    // wave-private, pad 104
    __shared__ __align__(16) float y[16][OUTD];
    const int tid = threadIdx.x, lane = tid & 63, wave = tid >> 6;
    const int b = blockIdx.x >> 5;
    const int n0 = (blockIdx.x & 31) * 16;
    const int cl = lane & 15, kq = lane >> 4;
    const float scale = 0.17677669529663687f;  // 1/sqrt(32)

    unsigned short* Pw = &P[wave][0];
    #pragma unroll
    for (int hh = 0; hh < 2; ++hh) {
        const int h = wave * 2 + hh;
        // ---- QK^T: logits [16 n][96 s], 6 MFMA ----
        bf16x8 aq = *(const bf16x8*)(qb + (size_t)(b * NN + n0 + cl) * 256 + h * 32 + kq * 8);
        f32x4 l[6];
        #pragma unroll
        for (int t = 0; t < 6; ++t) {
            bf16x8 bk = *(const bf16x8*)(kb + (size_t)(b * SS + t * 16 + cl) * 256 + h * 32 + kq * 8);
            l[t] = __builtin_amdgcn_mfma_f32_16x16x32_bf16(aq, bk, (f32x4){0.f,0.f,0.f,0.f}, 0, 0, 0);
        }
        // ---- softmax over s (D-layout: lane holds rows kq*4+r, col t*16+cl) ----
        float pr[6][4];
        float sum[4] = {0.f, 0.f, 0.f, 0.f};
        #pragma unroll
        for (int t = 0; t < 6; ++t)
            #pragma unroll
            for (int r = 0; r < 4; ++r) {
                float p = __expf(l[t][r] * scale);   // logits O(0.01): no max needed
                pr[t][r] = p; sum[r] += p;
            }
        #pragma unroll
        for (int r = 0; r < 4; ++r) {
            float s = sum[r];
            s += __shfl_xor(s, 1); s += __shfl_xor(s, 2);
            s += __shfl_xor(s, 4); s += __shfl_xor(s, 8);
            sum[r] = 1.0f / s;
        }
        // ---- P -> bf16 -> wave-private LDS [16 n][104] ----
        #pragma unroll
        for (int t = 0; t < 6; ++t)
            #pragma unroll
            for (int r = 0; r < 4; ++r)
                Pw[(kq * 4 + r) * 104 + t * 16 + cl] = f2bf(pr[t][r] * sum[r]);
        // ---- PV: ctx [16 n][32 d], 6 MFMA (A from P-lds, B from vT global) ----
        f32x4 c0 = (f32x4){0.f,0.f,0.f,0.f}, c1 = (f32x4){0.f,0.f,0.f,0.f};
        #pragma unroll
        for (int ks = 0; ks < 3; ++ks) {
            bf16x8 pa = *(const bf16x8*)(Pw + cl * 104 + ks * 32 + kq * 8);
            bf16x8 v0 = *(const bf16x8*)(vtb + (size_t)(b * 256 + h * 32 + cl) * 96 + ks * 32 + kq * 8);
            bf16x8 v1 = *(const bf16x8*)(vtb + (size_t)(b * 256 + h * 32 + 16 + cl) * 96 + ks * 32 + kq * 8);
            c0 = __builtin_amdgcn_mfma_f32_16x16x32_bf16(pa, v0, c0, 0, 0, 0);
            c1 = __builtin_amdgcn_mfma_f32_16x16x32_bf16(pa, v1, c1, 0, 0, 0);
        }
        // ---- ctx -> A0 (bf16, swizzled), cols h*32 .. h*32+31 ----
        #pragma unroll
        for (int dt = 0; dt < 2; ++dt) {
            const f32x4 cc = dt ? c1 : c0;
            const int C = h * 32 + dt * 16 + cl;
            const int slot = C >> 3, within = C & 7;
            #pragma unroll
            for (int r = 0; r < 4; ++r) {
                const int R = kq * 4 + r;
                A0[R * 256 + ((slot ^ (R & 7)) << 3) + within] = f2bf(cc[r]);
            }
        }
    }
    __syncthreads();

    // ---- head MLP (R4-validated) ----
    f32x4 acc[4];
    mfma_stage<4>(A0, bfw + WAOB_OFF, lane, wave, acc);
    epi_lds<4, false>(MID, bao, lane, wave, acc);
    __syncthreads();
    mfma_stage<4>(MID, bfw + W1B_OFF, lane, wave, acc);
    epi_lds<4, true>(A0, b1, lane, wave, acc);
    __syncthreads();
    {
        f32x4 a2[2];
        mfma_stage<2>(A0, bfw + WO1B_OFF, lane, wave, a2);
        const int rq = lane >> 4;
        #pragma unroll
        for (int ct = 0; ct < 2; ++ct) {
            const int C = wave * 32 + ct * 16 + cl;
            const float bb = bo1[C];
            #pragma unroll
            for (int r = 0; r < 4; ++r) {
                const int R = rq * 4 + r;
                H2[R * 128 + C] = fmaxf(a2[ct][r] + bb, 0.f);
            }
        }
    }
    __syncthreads();
    if (tid < 64) {
        int r = tid >> 2, o = tid & 3;
        float a = 0.f;
        const float4* w4 = (const float4*)(Wo2 + (size_t)o * 128);
        const float4* h4 = (const float4*)(H2 + r * 128);
        for (int kk = 0; kk < 32; ++kk) {
            float4 w = w4[kk], hv = h4[kk];
            a += hv.x * w.x + hv.y * w.y + hv.z * w.z + hv.w * w.w;
        }
        y[r][o] = a + bo2[o];
    }
    __syncthreads();
    const int nbase = n0;
    for (int i = tid; i < 16 * SS; i += 256) {
        int s = i >> 4;
        int r = i & 15;
        *(float4*)(out + ((size_t)(b * SS + s) * NN + (nbase + r)) * OUTD) = *(const float4*)y[r];
    }
}

extern "C" void kernel_launch(void* const* d_in, const int* in_sizes, int n_in,
                              void* d_out, int out_size, void* d_ws, size_t ws_size,
                              hipStream_t stream) {
    const float* spatial  = (const float*)d_in[0];
    const float* temporal = (const float*)d_in[1];
    const float* Ws  = (const float*)d_in[2];
    const float* bs  = (const float*)d_in[3];
    const float* Wt  = (const float*)d_in[4];
    const float* bt  = (const float*)d_in[5];
    const float* Win = (const float*)d_in[6];
    const float* bin = (const float*)d_in[7];
    const float* Wao = (const float*)d_in[8];
    const float* bao = (const float*)d_in[9];
    const float* W1  = (const float*)d_in[10];
    const float* b1  = (const float*)d_in[11];
    const float* Wo1 = (const float*)d_in[12];
    const float* bo1 = (const float*)d_in[13];
    const float* Wo2 = (const float*)d_in[14];
    const float* bo2 = (const float*)d_in[15];
    float* out = (float*)d_out;
    unsigned short* wsu = (unsigned short*)d_ws;

    unsigned short* bfw = wsu;
    unsigned short* qb  = wsu + QB_OFF;
    unsigned short* kb  = wsu + KB_OFF;
    unsigned short* vtb = wsu + VTB_OFF;

    hipLaunchKernelGGL(k_cast, dim3(120), dim3(256), 0, stream,
                       Ws, Wt, Win, Wao, W1, Wo1, bfw);
    hipLaunchKernelGGL(k_qkv, dim3(304), dim3(256), 0, stream,
                       spatial, temporal, bs, bt, bin, bfw, qb, kb, vtb);
    hipLaunchKernelGGL(k_attnhead, dim3(256), dim3(256), 0, stream,
                       qb, kb, vtb, bfw, bao, b1, bo1, Wo2, bo2, out);
}